// Round 9
// baseline (205.659 us; speedup 1.0000x reference)
//
#include <hip/hip_runtime.h>

constexpr int B_  = 4;
constexpr int T_  = 4096;
constexpr int C_  = 1024;
constexpr int H_  = 64;
constexpr int BT_ = B_ * T_;
constexpr int NUNIT_ = 576;    // 512-key units per batch: sum_qp ((qp>>4)+1), qp<128

typedef __attribute__((ext_vector_type(4))) float f32x4;
typedef __attribute__((ext_vector_type(8))) short bf16x8;
typedef __attribute__((ext_vector_type(8))) unsigned short u16x8;
typedef __attribute__((ext_vector_type(4))) unsigned short u16x4;

__device__ __forceinline__ unsigned short f32_to_bf16(float f) {
    union { float f; unsigned int u; } v;
    v.f = f;
    unsigned int r = v.u + 0x7FFFu + ((v.u >> 16) & 1u);  // RNE
    return (unsigned short)(r >> 16);
}
__device__ __forceinline__ float bf16_to_f32(unsigned short us) {
    union { unsigned int u; float f; } v;
    v.u = (unsigned int)us << 16;
    return v.f;
}
// 2^x via v_exp_f32 (hardware transcendental); __exp2f does not exist in HIP.
__device__ __forceinline__ float exp2_hw(float x) {
    return __builtin_amdgcn_exp2f(x);
}

// ---- Kernel 0: W -> fragment-order Wt (unchanged) --------------------------
__global__ __launch_bounds__(256) void wconv_kernel(
    const float* __restrict__ Wq, const float* __restrict__ Wk,
    const float* __restrict__ Wv, unsigned short* __restrict__ Wt)
{
    const int tid  = threadIdx.x;
    const int wid  = blockIdx.x * 4 + (tid >> 6);   // 0..383 = 12 ntiles x 32 ksteps
    const int lane = tid & 63;
    const int q    = lane >> 4, c = lane & 15;
    const int ntile = wid >> 5;
    const int kstep = wid & 31;
    const int n = ntile * 16 + c;                   // 0..191
    const int m = n >> 6;
    const float* W = (m == 0) ? Wq : (m == 1) ? Wk : Wv;
    const int ncol = n & 63;
    const int k0 = kstep * 32 + q * 8;
    u16x8 pk;
#pragma unroll
    for (int j = 0; j < 8; j++) pk[j] = f32_to_bf16(W[(size_t)(k0 + j) * H_ + ncol]);
    *(u16x8*)(Wt + (size_t)wid * 512 + lane * 8) = pk;
}

// ---- Kernel 1: QKV projection via bf16 MFMA (unchanged) --------------------
__global__ __launch_bounds__(256) void proj_kernel(
    const float* __restrict__ x, const unsigned short* __restrict__ Wt,
    unsigned short* __restrict__ Qb, unsigned short* __restrict__ Kb,
    unsigned short* __restrict__ Vb)
{
    __shared__ __align__(16) unsigned short xs[64][72];
    const int t    = threadIdx.x;
    const int rb   = blockIdx.x >> 1;
    const int ng   = blockIdx.x & 1;
    const int r0   = rb * 64;
    const int w    = t >> 6;
    const int lane = t & 63;
    const int quad = lane >> 4;
    const int c    = lane & 15;
    const int mh   = (w & 1) * 32;
    const int nh   = ng * 96 + (w >> 1) * 48;
    const int srow = t >> 2;        // 64 rows, 4 threads/row
    const int koff = (t & 3) * 16;  // 16 floats each

    f32x4 acc[2][3];
#pragma unroll
    for (int mi = 0; mi < 2; mi++)
#pragma unroll
        for (int j = 0; j < 3; j++) acc[mi][j] = {0.f, 0.f, 0.f, 0.f};

    const float* xp = x + (size_t)(r0 + srow) * C_ + koff;
    f32x4 v0 = *(const f32x4*)xp;
    f32x4 v1 = *(const f32x4*)(xp + 4);
    f32x4 v2 = *(const f32x4*)(xp + 8);
    f32x4 v3 = *(const f32x4*)(xp + 12);

    for (int kk = 0; kk < C_; kk += 64) {
        u16x8 p0, p1;
#pragma unroll
        for (int i = 0; i < 4; i++) {
            p0[i] = f32_to_bf16(v0[i]); p0[4 + i] = f32_to_bf16(v1[i]);
            p1[i] = f32_to_bf16(v2[i]); p1[4 + i] = f32_to_bf16(v3[i]);
        }
        __syncthreads();
        *(u16x8*)&xs[srow][koff]     = p0;
        *(u16x8*)&xs[srow][koff + 8] = p1;
        __syncthreads();
        if (kk + 64 < C_) {     // register prefetch of next x tile
            v0 = *(const f32x4*)(xp + kk + 64);
            v1 = *(const f32x4*)(xp + kk + 68);
            v2 = *(const f32x4*)(xp + kk + 72);
            v3 = *(const f32x4*)(xp + kk + 76);
        }
#pragma unroll
        for (int ks = 0; ks < 64; ks += 32) {
            const bf16x8 a0 = *(const bf16x8*)&xs[mh + c][ks + quad * 8];
            const bf16x8 a1 = *(const bf16x8*)&xs[mh + 16 + c][ks + quad * 8];
            const unsigned short* bp =
                Wt + ((size_t)(nh >> 4) * 32 + ((kk + ks) >> 5)) * 512 + lane * 8;
#pragma unroll
            for (int j = 0; j < 3; j++) {
                const bf16x8 bj = *(const bf16x8*)(bp + (size_t)j * 32 * 512);
                acc[0][j] = __builtin_amdgcn_mfma_f32_16x16x32_bf16(a0, bj, acc[0][j], 0, 0, 0);
                acc[1][j] = __builtin_amdgcn_mfma_f32_16x16x32_bf16(a1, bj, acc[1][j], 0, 0, 0);
            }
        }
    }

#pragma unroll
    for (int mi = 0; mi < 2; mi++) {
#pragma unroll
        for (int j = 0; j < 3; j++) {
            const int nt = nh + j * 16;      // 16-aligned -> wave-uniform select
            unsigned short* dst = (nt < 64) ? (Qb + nt)
                                : (nt < 128) ? (Kb + nt - 64)
                                             : (Vb + nt - 128);
#pragma unroll
            for (int r = 0; r < 4; r++) {
                const size_t row = (size_t)r0 + mh + mi * 16 + quad * 4 + r;
                dst[row * H_ + c] = f32_to_bf16(acc[mi][j][r]);
            }
        }
    }
}

// ---- Kernel 2: K,V -> fragment order (Kf, Vf) (unchanged) ------------------
__global__ __launch_bounds__(256) void prep_kernel(
    const unsigned short* __restrict__ Kb, const unsigned short* __restrict__ Vb,
    unsigned short* __restrict__ Kf, unsigned short* __restrict__ Vf)
{
    __shared__ __align__(16) unsigned short vs[64][72];
    const int t    = threadIdx.x;
    const int r0   = blockIdx.x * 64;       // global row (64 | 4096: no b-cross)
    const int b    = r0 >> 12;
    const int kloc = r0 & 4095;
    const int w    = t >> 6, lane = t & 63, q = lane >> 4, c = lane & 15;

    // stage V tile: 64 rows x 64 cols; each thread stores 16 shorts
    const int row = t >> 2, col = (t & 3) * 16;
    const unsigned short* vsrc = Vb + (size_t)(r0 + row) * H_ + col;
    u16x8 va0 = *(const u16x8*)vsrc;
    u16x8 va1 = *(const u16x8*)(vsrc + 8);
    *(u16x8*)&vs[row][col]     = va0;
    *(u16x8*)&vs[row][col + 8] = va1;

    // K reorder (register-only)
    const unsigned short* ksrc = Kb + (size_t)(r0 + w * 16 + c) * H_ + q * 8;
    u16x8 k0v = *(const u16x8*)ksrc;
    u16x8 k1v = *(const u16x8*)(ksrc + 32);
    const size_t kt = (size_t)b * 256 + (kloc >> 4) + w;
    *(u16x8*)(Kf + kt * 1024 + lane * 8)       = k0v;
    *(u16x8*)(Kf + kt * 1024 + 512 + lane * 8) = k1v;

    __syncthreads();
    // V frags: wave w = h-tile
#pragma unroll
    for (int kh = 0; kh < 2; kh++) {
        u16x8 pv;
#pragma unroll
        for (int j = 0; j < 8; j++) pv[j] = vs[kh * 32 + q * 8 + j][w * 16 + c];
        const size_t k32 = (size_t)b * 128 + (kloc >> 5) + kh;
        *(u16x8*)(Vf + (k32 * 4 + w) * 512 + lane * 8) = pv;
    }
}

// ---- Kernel 3: causal flash attention, 32-query units (round-9 change) -----
// Unit = wave = (b, qp, ks): queries qp*32..+31 (TWO 16-q tiles sharing every
// K/V fragment load -> halves L2/L3 K/V traffic), keys [ks*512, +512).
// qp in LOW bits of bid (XCD balance), descending. Valid iff ks <= qp>>4.
__global__ __launch_bounds__(256) void attn_kernel(
    const unsigned short* __restrict__ Qb, const unsigned short* __restrict__ Kf,
    const unsigned short* __restrict__ Vf, unsigned short* __restrict__ Opg,
    float* __restrict__ mlg)
{
    __shared__ __align__(16) unsigned short Pb[4][2][16][72];  // per-wave A/B bufs
    const int tid  = threadIdx.x;
    const int w    = tid >> 6;
    const int lane = tid & 63;
    const int quad = lane >> 4;
    const int c    = lane & 15;
    const int bid  = blockIdx.x;
    const int qp   = 127 - (bid & 127);
    const int ks   = bid >> 7;
    const int g    = qp >> 4;                 // nseg-1
    if (ks > g) return;
    const int b    = w;                       // wave = batch
    const int q0   = qp * 32;
    const int k0   = ks * 512;
    const int kend = (q0 + 31 < k0 + 511) ? q0 + 31 : k0 + 511;
    const size_t bT = (size_t)b * T_;

    // Q B-frags for both 16-query tiles
    const unsigned short* qpa = Qb + (bT + q0 + c) * H_ + quad * 8;
    const bf16x8 qB0a = *(const bf16x8*)qpa;
    const bf16x8 qB1a = *(const bf16x8*)(qpa + 32);
    const unsigned short* qpb = qpa + 16 * H_;
    const bf16x8 qB0b = *(const bf16x8*)qpb;
    const bf16x8 qB1b = *(const bf16x8*)(qpb + 32);

    f32x4 Oa[4], Ob[4];
#pragma unroll
    for (int tt = 0; tt < 4; tt++) { Oa[tt] = {0.f,0.f,0.f,0.f}; Ob[tt] = {0.f,0.f,0.f,0.f}; }
    float ma = -1e30f, lsa = 0.f;
    float mb = -1e30f, lsb = 0.f;
    const float scale2 = 0.045084436f;        // (1/32)*log2(e): exp -> exp2

    unsigned short* Pa = &Pb[w][0][0][0];
    unsigned short* Pc = &Pb[w][1][0][0];
    const int prow = c * 72;

    for (int kb = k0; kb <= kend; kb += 64) {
        const unsigned short* kfb = Kf + ((size_t)b * 256 + (kb >> 4)) * 1024 + lane * 8;
        f32x4 Sa[4], Sb[4];
#pragma unroll
        for (int tt = 0; tt < 4; tt++) {
            const bf16x8 kA0 = *(const bf16x8*)(kfb + tt * 1024);
            const bf16x8 kA1 = *(const bf16x8*)(kfb + tt * 1024 + 512);
            f32x4 s = {0.f, 0.f, 0.f, 0.f};
            s = __builtin_amdgcn_mfma_f32_16x16x32_bf16(kA0, qB0a, s, 0, 0, 0);
            s = __builtin_amdgcn_mfma_f32_16x16x32_bf16(kA1, qB1a, s, 0, 0, 0);
            Sa[tt] = s;
            f32x4 u = {0.f, 0.f, 0.f, 0.f};
            u = __builtin_amdgcn_mfma_f32_16x16x32_bf16(kA0, qB0b, u, 0, 0, 0);
            u = __builtin_amdgcn_mfma_f32_16x16x32_bf16(kA1, qB1b, u, 0, 0, 0);
            Sb[tt] = u;
        }

        // ---- tile A softmax (queries q0..q0+15) ----
        {
            float sc[16];
            if (kb + 63 > q0) {
#pragma unroll
                for (int tt = 0; tt < 4; tt++)
#pragma unroll
                    for (int r = 0; r < 4; r++) {
                        const int key = kb + tt * 16 + quad * 4 + r;
                        sc[tt * 4 + r] = (key > q0 + c) ? -1e30f : Sa[tt][r] * scale2;
                    }
            } else {
#pragma unroll
                for (int tt = 0; tt < 4; tt++)
#pragma unroll
                    for (int r = 0; r < 4; r++) sc[tt * 4 + r] = Sa[tt][r] * scale2;
            }
            float mx = sc[0];
#pragma unroll
            for (int i = 1; i < 16; i++) mx = fmaxf(mx, sc[i]);
            mx = fmaxf(mx, __shfl_xor(mx, 16));
            mx = fmaxf(mx, __shfl_xor(mx, 32));
            const float mn    = fmaxf(ma, mx);
            const float alpha = exp2_hw(ma - mn);
            ma = mn;
            float lsum = 0.f;
#pragma unroll
            for (int tt = 0; tt < 4; tt++) {
                u16x4 pk;
#pragma unroll
                for (int r = 0; r < 4; r++) {
                    const float e = exp2_hw(sc[tt * 4 + r] - mn);
                    lsum += e;
                    pk[r] = f32_to_bf16(e);
                }
                *(u16x4*)(Pa + prow + tt * 16 + quad * 4) = pk;
            }
            lsa = lsa * alpha + lsum;
#pragma unroll
            for (int tt = 0; tt < 4; tt++)
#pragma unroll
                for (int r = 0; r < 4; r++) Oa[tt][r] *= alpha;
        }
        // ---- tile B softmax (queries q0+16..q0+31) ----
        {
            const int q0b = q0 + 16;
            float sc[16];
            if (kb + 63 > q0b) {
#pragma unroll
                for (int tt = 0; tt < 4; tt++)
#pragma unroll
                    for (int r = 0; r < 4; r++) {
                        const int key = kb + tt * 16 + quad * 4 + r;
                        sc[tt * 4 + r] = (key > q0b + c) ? -1e30f : Sb[tt][r] * scale2;
                    }
            } else {
#pragma unroll
                for (int tt = 0; tt < 4; tt++)
#pragma unroll
                    for (int r = 0; r < 4; r++) sc[tt * 4 + r] = Sb[tt][r] * scale2;
            }
            float mx = sc[0];
#pragma unroll
            for (int i = 1; i < 16; i++) mx = fmaxf(mx, sc[i]);
            mx = fmaxf(mx, __shfl_xor(mx, 16));
            mx = fmaxf(mx, __shfl_xor(mx, 32));
            const float mn    = fmaxf(mb, mx);
            const float alpha = exp2_hw(mb - mn);
            mb = mn;
            float lsum = 0.f;
#pragma unroll
            for (int tt = 0; tt < 4; tt++) {
                u16x4 pk;
#pragma unroll
                for (int r = 0; r < 4; r++) {
                    const float e = exp2_hw(sc[tt * 4 + r] - mn);
                    lsum += e;
                    pk[r] = f32_to_bf16(e);
                }
                *(u16x4*)(Pc + prow + tt * 16 + quad * 4) = pk;
            }
            lsb = lsb * alpha + lsum;
#pragma unroll
            for (int tt = 0; tt < 4; tt++)
#pragma unroll
                for (int r = 0; r < 4; r++) Ob[tt][r] *= alpha;
        }

        const bf16x8 pB0a = *(const bf16x8*)(Pa + prow + quad * 8);
        const bf16x8 pB1a = *(const bf16x8*)(Pa + prow + 32 + quad * 8);
        const bf16x8 pB0b = *(const bf16x8*)(Pc + prow + quad * 8);
        const bf16x8 pB1b = *(const bf16x8*)(Pc + prow + 32 + quad * 8);

        const unsigned short* vfb = Vf + ((size_t)b * 128 + (kb >> 5)) * 2048 + lane * 8;
#pragma unroll
        for (int tt = 0; tt < 4; tt++) {
            const bf16x8 vA0 = *(const bf16x8*)(vfb + tt * 512);
            const bf16x8 vA1 = *(const bf16x8*)(vfb + 2048 + tt * 512);
            Oa[tt] = __builtin_amdgcn_mfma_f32_16x16x32_bf16(vA0, pB0a, Oa[tt], 0, 0, 0);
            Oa[tt] = __builtin_amdgcn_mfma_f32_16x16x32_bf16(vA1, pB1a, Oa[tt], 0, 0, 0);
            Ob[tt] = __builtin_amdgcn_mfma_f32_16x16x32_bf16(vA0, pB0b, Ob[tt], 0, 0, 0);
            Ob[tt] = __builtin_amdgcn_mfma_f32_16x16x32_bf16(vA1, pB1b, Ob[tt], 0, 0, 0);
        }
    }

    lsa += __shfl_xor(lsa, 16); lsa += __shfl_xor(lsa, 32);
    lsb += __shfl_xor(lsb, 16); lsb += __shfl_xor(lsb, 32);

    // unit index: offset(qp) = qp + 8g(g-1) + g*(qp&15)
    const size_t ustore = (size_t)b * NUNIT_ + qp + 8 * g * (g - 1) + g * (qp & 15) + ks;
#pragma unroll
    for (int tt = 0; tt < 4; tt++) {
        u16x4 pka, pkb;
#pragma unroll
        for (int r = 0; r < 4; r++) { pka[r] = f32_to_bf16(Oa[tt][r]); pkb[r] = f32_to_bf16(Ob[tt][r]); }
        *(u16x4*)(Opg + ustore * 2048 + c * 64        + tt * 16 + quad * 4) = pka;
        *(u16x4*)(Opg + ustore * 2048 + (16 + c) * 64 + tt * 16 + quad * 4) = pkb;
    }
    if (lane < 16) {
        mlg[ustore * 64 + c]      = ma;       // m, queries 0..15
        mlg[ustore * 64 + 16 + c] = mb;       // m, queries 16..31
        mlg[ustore * 64 + 32 + c] = lsa;      // l, queries 0..15
        mlg[ustore * 64 + 48 + c] = lsb;      // l, queries 16..31
    }
}

// ---- Kernel 4: merge segments + normalize (32-query units) -----------------
__global__ __launch_bounds__(256) void merge_kernel(
    const unsigned short* __restrict__ Opg, const float* __restrict__ mlg,
    float* __restrict__ out)
{
    const int idx = blockIdx.x;               // 512 = b*128 + qp
    const int b   = idx >> 7;
    const int qp  = idx & 127;
    const int g   = qp >> 4;
    const int nseg = g + 1;
    const size_t base = (size_t)b * NUNIT_ + qp + 8 * g * (g - 1) + g * (qp & 15);
    const int t  = threadIdx.x;
    const int h  = t & 63;
    const int rg = t >> 6;
#pragma unroll
    for (int i = 0; i < 8; i++) {
        const int row = rg * 8 + i;           // 0..31
        float M = -1e30f;
        for (int s = 0; s < nseg; s++) M = fmaxf(M, mlg[(base + s) * 64 + row]);
        float L = 0.f, val = 0.f;
        for (int s = 0; s < nseg; s++) {
            const float e = exp2_hw(mlg[(base + s) * 64 + row] - M);
            L   = fmaf(mlg[(base + s) * 64 + 32 + row], e, L);
            val = fmaf(bf16_to_f32(Opg[(base + s) * 2048 + row * 64 + h]), e, val);
        }
        out[((size_t)b * T_ + qp * 32 + row) * H_ + h] = val / L;
    }
}

extern "C" void kernel_launch(void* const* d_in, const int* in_sizes, int n_in,
                              void* d_out, int out_size, void* d_ws, size_t ws_size,
                              hipStream_t stream) {
    const float* x  = (const float*)d_in[0];
    const float* Wq = (const float*)d_in[1];
    const float* Wk = (const float*)d_in[2];
    const float* Wv = (const float*)d_in[3];
    float* out = (float*)d_out;

    // ws: Qb|Kb|Vb|Kf|Vf (2 MiB each) | Wt 384K | Opg 9.4 MiB | mlg 590K
    unsigned short* Qb = (unsigned short*)d_ws;
    unsigned short* Kb = Qb + (size_t)BT_ * H_;
    unsigned short* Vb = Kb + (size_t)BT_ * H_;
    unsigned short* Kf = Vb + (size_t)BT_ * H_;
    unsigned short* Vf = Kf + (size_t)BT_ * H_;
    unsigned short* Wt = Vf + (size_t)BT_ * H_;
    unsigned short* Opg = Wt + (size_t)192 * C_;
    float*          mlg = (float*)(Opg + (size_t)B_ * NUNIT_ * 2048);

    wconv_kernel<<<96, 256, 0, stream>>>(Wq, Wk, Wv, Wt);
    proj_kernel<<<512, 256, 0, stream>>>(x, Wt, Qb, Kb, Vb);
    prep_kernel<<<BT_ / 64, 256, 0, stream>>>(Kb, Vb, Kf, Vf);
    attn_kernel<<<1024, 256, 0, stream>>>(Qb, Kf, Vf, Opg, mlg);
    merge_kernel<<<512, 256, 0, stream>>>(Opg, mlg, out);
}

// Round 10
// 181.163 us; speedup vs baseline: 1.1352x; 1.1352x over previous
//
#include <hip/hip_runtime.h>

constexpr int B_  = 4;
constexpr int T_  = 4096;
constexpr int C_  = 1024;
constexpr int H_  = 64;
constexpr int BT_ = B_ * T_;
constexpr int NUNIT_ = 2176;   // 256-key units per batch: sum_qt ((qt>>4)+1)

typedef __attribute__((ext_vector_type(4))) float f32x4;
typedef __attribute__((ext_vector_type(8))) short bf16x8;
typedef __attribute__((ext_vector_type(8))) unsigned short u16x8;
typedef __attribute__((ext_vector_type(4))) unsigned short u16x4;

__device__ __forceinline__ unsigned short f32_to_bf16(float f) {
    union { float f; unsigned int u; } v;
    v.f = f;
    unsigned int r = v.u + 0x7FFFu + ((v.u >> 16) & 1u);  // RNE
    return (unsigned short)(r >> 16);
}
__device__ __forceinline__ float bf16_to_f32(unsigned short us) {
    union { unsigned int u; float f; } v;
    v.u = (unsigned int)us << 16;
    return v.f;
}
// 2^x via v_exp_f32 (hardware transcendental); __exp2f does not exist in HIP.
__device__ __forceinline__ float exp2_hw(float x) {
    return __builtin_amdgcn_exp2f(x);
}

// ---- Kernel 0: W -> fragment-order Wt (unchanged) --------------------------
__global__ __launch_bounds__(256) void wconv_kernel(
    const float* __restrict__ Wq, const float* __restrict__ Wk,
    const float* __restrict__ Wv, unsigned short* __restrict__ Wt)
{
    const int tid  = threadIdx.x;
    const int wid  = blockIdx.x * 4 + (tid >> 6);   // 0..383 = 12 ntiles x 32 ksteps
    const int lane = tid & 63;
    const int q    = lane >> 4, c = lane & 15;
    const int ntile = wid >> 5;
    const int kstep = wid & 31;
    const int n = ntile * 16 + c;                   // 0..191
    const int m = n >> 6;
    const float* W = (m == 0) ? Wq : (m == 1) ? Wk : Wv;
    const int ncol = n & 63;
    const int k0 = kstep * 32 + q * 8;
    u16x8 pk;
#pragma unroll
    for (int j = 0; j < 8; j++) pk[j] = f32_to_bf16(W[(size_t)(k0 + j) * H_ + ncol]);
    *(u16x8*)(Wt + (size_t)wid * 512 + lane * 8) = pk;
}

// ---- Kernel 1: QKV projection via bf16 MFMA (unchanged) --------------------
__global__ __launch_bounds__(256) void proj_kernel(
    const float* __restrict__ x, const unsigned short* __restrict__ Wt,
    unsigned short* __restrict__ Qb, unsigned short* __restrict__ Kb,
    unsigned short* __restrict__ Vb)
{
    __shared__ __align__(16) unsigned short xs[64][72];
    const int t    = threadIdx.x;
    const int rb   = blockIdx.x >> 1;
    const int ng   = blockIdx.x & 1;
    const int r0   = rb * 64;
    const int w    = t >> 6;
    const int lane = t & 63;
    const int quad = lane >> 4;
    const int c    = lane & 15;
    const int mh   = (w & 1) * 32;
    const int nh   = ng * 96 + (w >> 1) * 48;
    const int srow = t >> 2;        // 64 rows, 4 threads/row
    const int koff = (t & 3) * 16;  // 16 floats each

    f32x4 acc[2][3];
#pragma unroll
    for (int mi = 0; mi < 2; mi++)
#pragma unroll
        for (int j = 0; j < 3; j++) acc[mi][j] = {0.f, 0.f, 0.f, 0.f};

    const float* xp = x + (size_t)(r0 + srow) * C_ + koff;
    f32x4 v0 = *(const f32x4*)xp;
    f32x4 v1 = *(const f32x4*)(xp + 4);
    f32x4 v2 = *(const f32x4*)(xp + 8);
    f32x4 v3 = *(const f32x4*)(xp + 12);

    for (int kk = 0; kk < C_; kk += 64) {
        u16x8 p0, p1;
#pragma unroll
        for (int i = 0; i < 4; i++) {
            p0[i] = f32_to_bf16(v0[i]); p0[4 + i] = f32_to_bf16(v1[i]);
            p1[i] = f32_to_bf16(v2[i]); p1[4 + i] = f32_to_bf16(v3[i]);
        }
        __syncthreads();
        *(u16x8*)&xs[srow][koff]     = p0;
        *(u16x8*)&xs[srow][koff + 8] = p1;
        __syncthreads();
        if (kk + 64 < C_) {     // register prefetch of next x tile
            v0 = *(const f32x4*)(xp + kk + 64);
            v1 = *(const f32x4*)(xp + kk + 68);
            v2 = *(const f32x4*)(xp + kk + 72);
            v3 = *(const f32x4*)(xp + kk + 76);
        }
#pragma unroll
        for (int ks = 0; ks < 64; ks += 32) {
            const bf16x8 a0 = *(const bf16x8*)&xs[mh + c][ks + quad * 8];
            const bf16x8 a1 = *(const bf16x8*)&xs[mh + 16 + c][ks + quad * 8];
            const unsigned short* bp =
                Wt + ((size_t)(nh >> 4) * 32 + ((kk + ks) >> 5)) * 512 + lane * 8;
#pragma unroll
            for (int j = 0; j < 3; j++) {
                const bf16x8 bj = *(const bf16x8*)(bp + (size_t)j * 32 * 512);
                acc[0][j] = __builtin_amdgcn_mfma_f32_16x16x32_bf16(a0, bj, acc[0][j], 0, 0, 0);
                acc[1][j] = __builtin_amdgcn_mfma_f32_16x16x32_bf16(a1, bj, acc[1][j], 0, 0, 0);
            }
        }
    }

#pragma unroll
    for (int mi = 0; mi < 2; mi++) {
#pragma unroll
        for (int j = 0; j < 3; j++) {
            const int nt = nh + j * 16;      // 16-aligned -> wave-uniform select
            unsigned short* dst = (nt < 64) ? (Qb + nt)
                                : (nt < 128) ? (Kb + nt - 64)
                                             : (Vb + nt - 128);
#pragma unroll
            for (int r = 0; r < 4; r++) {
                const size_t row = (size_t)r0 + mh + mi * 16 + quad * 4 + r;
                dst[row * H_ + c] = f32_to_bf16(acc[mi][j][r]);
            }
        }
    }
}

// ---- Kernel 2: K,V -> fragment order (Kf, Vf) (unchanged) ------------------
__global__ __launch_bounds__(256) void prep_kernel(
    const unsigned short* __restrict__ Kb, const unsigned short* __restrict__ Vb,
    unsigned short* __restrict__ Kf, unsigned short* __restrict__ Vf)
{
    __shared__ __align__(16) unsigned short vs[64][72];
    const int t    = threadIdx.x;
    const int r0   = blockIdx.x * 64;       // global row (64 | 4096: no b-cross)
    const int b    = r0 >> 12;
    const int kloc = r0 & 4095;
    const int w    = t >> 6, lane = t & 63, q = lane >> 4, c = lane & 15;

    // stage V tile: 64 rows x 64 cols; each thread stores 16 shorts
    const int row = t >> 2, col = (t & 3) * 16;
    const unsigned short* vsrc = Vb + (size_t)(r0 + row) * H_ + col;
    u16x8 va0 = *(const u16x8*)vsrc;
    u16x8 va1 = *(const u16x8*)(vsrc + 8);
    *(u16x8*)&vs[row][col]     = va0;
    *(u16x8*)&vs[row][col + 8] = va1;

    // K reorder (register-only)
    const unsigned short* ksrc = Kb + (size_t)(r0 + w * 16 + c) * H_ + q * 8;
    u16x8 k0v = *(const u16x8*)ksrc;
    u16x8 k1v = *(const u16x8*)(ksrc + 32);
    const size_t kt = (size_t)b * 256 + (kloc >> 4) + w;
    *(u16x8*)(Kf + kt * 1024 + lane * 8)       = k0v;
    *(u16x8*)(Kf + kt * 1024 + 512 + lane * 8) = k1v;

    __syncthreads();
    // V frags: wave w = h-tile
#pragma unroll
    for (int kh = 0; kh < 2; kh++) {
        u16x8 pv;
#pragma unroll
        for (int j = 0; j < 8; j++) pv[j] = vs[kh * 32 + q * 8 + j][w * 16 + c];
        const size_t k32 = (size_t)b * 128 + (kloc >> 5) + kh;
        *(u16x8*)(Vf + (k32 * 4 + w) * 512 + lane * 8) = pv;
    }
}

// ---- Kernel 3: causal flash attention, 256-key units (round-10 change) -----
// Round-9 falsified the traffic theory: attn is LATENCY-bound; residency is
// the lever. Revert to 16-query units (VGPR ~68 -> 7 waves/SIMD) and shrink
// segments 512->256: 8704 valid waves (~8.5/SIMD demand) vs round-8's 4608.
// qt in LOW bits (XCD balance), ks in high bits. Valid iff ks <= qt>>4.
__global__ __launch_bounds__(256) void attn_kernel(
    const unsigned short* __restrict__ Qb, const unsigned short* __restrict__ Kf,
    const unsigned short* __restrict__ Vf, unsigned short* __restrict__ Opg,
    float* __restrict__ mlg)
{
    __shared__ __align__(16) unsigned short Pb[4][16][72];
    const int tid  = threadIdx.x;
    const int w    = tid >> 6;
    const int lane = tid & 63;
    const int quad = lane >> 4;
    const int c    = lane & 15;
    const int bid  = blockIdx.x;
    const int qt   = 255 - (bid & 255);       // qt descending within ks-group
    const int ks   = bid >> 8;                // 0..15
    const int g    = qt >> 4;                 // nseg-1
    if (ks > g) return;
    const int b    = w;                       // wave = batch (equal work lengths)
    const int q0   = qt * 16;
    const int k0   = ks * 256;
    const int kend = (q0 + 15 < k0 + 255) ? q0 + 15 : k0 + 255;
    const size_t bT = (size_t)b * T_;

    const unsigned short* qp = Qb + (bT + q0 + c) * H_ + quad * 8;
    const bf16x8 qB0 = *(const bf16x8*)qp;
    const bf16x8 qB1 = *(const bf16x8*)(qp + 32);

    f32x4 O[4];
#pragma unroll
    for (int tt = 0; tt < 4; tt++) O[tt] = {0.f, 0.f, 0.f, 0.f};
    float m = -1e30f, ls = 0.f;
    const float scale2 = 0.045084436f;        // (1/32)*log2(e): exp -> exp2

    unsigned short* P = &Pb[w][0][0];
    const int prow = c * 72;

    for (int kb = k0; kb <= kend; kb += 64) {
        const unsigned short* kfb = Kf + ((size_t)b * 256 + (kb >> 4)) * 1024 + lane * 8;
        f32x4 S[4];
#pragma unroll
        for (int tt = 0; tt < 4; tt++) {
            const bf16x8 kA0 = *(const bf16x8*)(kfb + tt * 1024);
            const bf16x8 kA1 = *(const bf16x8*)(kfb + tt * 1024 + 512);
            f32x4 s = {0.f, 0.f, 0.f, 0.f};
            s = __builtin_amdgcn_mfma_f32_16x16x32_bf16(kA0, qB0, s, 0, 0, 0);
            s = __builtin_amdgcn_mfma_f32_16x16x32_bf16(kA1, qB1, s, 0, 0, 0);
            S[tt] = s;
        }
        float sc[16];
        if (kb + 63 > q0) {                   // diagonal chunk: causal mask
#pragma unroll
            for (int tt = 0; tt < 4; tt++)
#pragma unroll
                for (int r = 0; r < 4; r++) {
                    const int key = kb + tt * 16 + quad * 4 + r;
                    sc[tt * 4 + r] = (key > q0 + c) ? -1e30f : S[tt][r] * scale2;
                }
        } else {
#pragma unroll
            for (int tt = 0; tt < 4; tt++)
#pragma unroll
                for (int r = 0; r < 4; r++) sc[tt * 4 + r] = S[tt][r] * scale2;
        }
        float mx = sc[0];
#pragma unroll
        for (int i = 1; i < 16; i++) mx = fmaxf(mx, sc[i]);
        mx = fmaxf(mx, __shfl_xor(mx, 16));
        mx = fmaxf(mx, __shfl_xor(mx, 32));
        const float mn    = fmaxf(m, mx);
        const float alpha = exp2_hw(m - mn);
        m = mn;
        float lsum = 0.f;
#pragma unroll
        for (int tt = 0; tt < 4; tt++) {
            u16x4 pk;
#pragma unroll
            for (int r = 0; r < 4; r++) {
                const float e = exp2_hw(sc[tt * 4 + r] - mn);
                lsum += e;
                pk[r] = f32_to_bf16(e);
            }
            *(u16x4*)(P + prow + tt * 16 + quad * 4) = pk;   // P[query][key]
        }
        ls = ls * alpha + lsum;                // per-lane partial (this quad's keys)
#pragma unroll
        for (int tt = 0; tt < 4; tt++)
#pragma unroll
            for (int r = 0; r < 4; r++) O[tt][r] *= alpha;

        const bf16x8 pB0 = *(const bf16x8*)(P + prow + quad * 8);
        const bf16x8 pB1 = *(const bf16x8*)(P + prow + 32 + quad * 8);

        const unsigned short* vfb = Vf + ((size_t)b * 128 + (kb >> 5)) * 2048 + lane * 8;
#pragma unroll
        for (int tt = 0; tt < 4; tt++) {
            const bf16x8 vA0 = *(const bf16x8*)(vfb + tt * 512);
            const bf16x8 vA1 = *(const bf16x8*)(vfb + 2048 + tt * 512);
            O[tt] = __builtin_amdgcn_mfma_f32_16x16x32_bf16(vA0, pB0, O[tt], 0, 0, 0);
            O[tt] = __builtin_amdgcn_mfma_f32_16x16x32_bf16(vA1, pB1, O[tt], 0, 0, 0);
        }
    }

    ls += __shfl_xor(ls, 16);                 // total l for query c
    ls += __shfl_xor(ls, 32);

    // offset(qt) = qt + 8g(g-1) + g*(qt&15);  max -> 2176 = NUNIT_
    const size_t ustore = (size_t)b * NUNIT_ + qt + 8 * g * (g - 1) + g * (qt & 15) + ks;
#pragma unroll
    for (int tt = 0; tt < 4; tt++) {
        u16x4 pk;
#pragma unroll
        for (int r = 0; r < 4; r++) pk[r] = f32_to_bf16(O[tt][r]);
        *(u16x4*)(Opg + ustore * 1024 + c * 64 + tt * 16 + quad * 4) = pk;
    }
    if (lane < 16) {
        mlg[ustore * 32 + c]      = m;        // log2-domain max
        mlg[ustore * 32 + 16 + c] = ls;
    }
}

// ---- Kernel 4: merge segments + normalize (<=16 segments) ------------------
__global__ __launch_bounds__(256) void merge_kernel(
    const unsigned short* __restrict__ Opg, const float* __restrict__ mlg,
    float* __restrict__ out)
{
    const int idx = blockIdx.x;               // 1024 = b*256 + qt
    const int b   = idx >> 8;
    const int qt  = idx & 255;
    const int g   = qt >> 4;
    const int nseg = g + 1;
    const size_t base = (size_t)b * NUNIT_ + qt + 8 * g * (g - 1) + g * (qt & 15);
    const int t  = threadIdx.x;
    const int h  = t & 63;
    const int rg = t >> 6;
#pragma unroll
    for (int i = 0; i < 4; i++) {
        const int row = rg * 4 + i;
        float M = -1e30f;
        for (int s = 0; s < nseg; s++) M = fmaxf(M, mlg[(base + s) * 32 + row]);
        float L = 0.f, val = 0.f;
        for (int s = 0; s < nseg; s++) {
            const float e = exp2_hw(mlg[(base + s) * 32 + row] - M);
            L   = fmaf(mlg[(base + s) * 32 + 16 + row], e, L);
            val = fmaf(bf16_to_f32(Opg[(base + s) * 1024 + row * 64 + h]), e, val);
        }
        out[((size_t)b * T_ + qt * 16 + row) * H_ + h] = val / L;
    }
}

extern "C" void kernel_launch(void* const* d_in, const int* in_sizes, int n_in,
                              void* d_out, int out_size, void* d_ws, size_t ws_size,
                              hipStream_t stream) {
    const float* x  = (const float*)d_in[0];
    const float* Wq = (const float*)d_in[1];
    const float* Wk = (const float*)d_in[2];
    const float* Wv = (const float*)d_in[3];
    float* out = (float*)d_out;

    // ws: Qb|Kb|Vb|Kf|Vf (2 MiB each) | Wt 384K | Opg 17.8 MiB | mlg 1.1 MiB
    unsigned short* Qb = (unsigned short*)d_ws;
    unsigned short* Kb = Qb + (size_t)BT_ * H_;
    unsigned short* Vb = Kb + (size_t)BT_ * H_;
    unsigned short* Kf = Vb + (size_t)BT_ * H_;
    unsigned short* Vf = Kf + (size_t)BT_ * H_;
    unsigned short* Wt = Vf + (size_t)BT_ * H_;
    unsigned short* Opg = Wt + (size_t)192 * C_;
    float*          mlg = (float*)(Opg + (size_t)B_ * NUNIT_ * 1024);

    wconv_kernel<<<96, 256, 0, stream>>>(Wq, Wk, Wv, Wt);
    proj_kernel<<<512, 256, 0, stream>>>(x, Wt, Qb, Kb, Vb);
    prep_kernel<<<BT_ / 64, 256, 0, stream>>>(Kb, Vb, Kf, Vf);
    attn_kernel<<<4096, 256, 0, stream>>>(Qb, Kf, Vf, Opg, mlg);
    merge_kernel<<<1024, 256, 0, stream>>>(Opg, mlg, out);
}

// Round 11
// 170.115 us; speedup vs baseline: 1.2089x; 1.0649x over previous
//
#include <hip/hip_runtime.h>

constexpr int B_  = 4;
constexpr int T_  = 4096;
constexpr int C_  = 1024;
constexpr int H_  = 64;
constexpr int BT_ = B_ * T_;
constexpr int NUNIT_ = 1152;   // 512-key work units per batch: sum_qt (qt/32+1)

typedef __attribute__((ext_vector_type(4))) float f32x4;
typedef __attribute__((ext_vector_type(8))) short bf16x8;
typedef __attribute__((ext_vector_type(8))) unsigned short u16x8;
typedef __attribute__((ext_vector_type(4))) unsigned short u16x4;

__device__ __forceinline__ unsigned short f32_to_bf16(float f) {
    union { float f; unsigned int u; } v;
    v.f = f;
    unsigned int r = v.u + 0x7FFFu + ((v.u >> 16) & 1u);  // RNE
    return (unsigned short)(r >> 16);
}
__device__ __forceinline__ float bf16_to_f32(unsigned short us) {
    union { unsigned int u; float f; } v;
    v.u = (unsigned int)us << 16;
    return v.f;
}
// 2^x via v_exp_f32 (hardware transcendental); __exp2f does not exist in HIP.
__device__ __forceinline__ float exp2_hw(float x) {
    return __builtin_amdgcn_exp2f(x);
}

// ---- Kernel 0: W -> fragment-order Wt (unchanged) --------------------------
__global__ __launch_bounds__(256) void wconv_kernel(
    const float* __restrict__ Wq, const float* __restrict__ Wk,
    const float* __restrict__ Wv, unsigned short* __restrict__ Wt)
{
    const int tid  = threadIdx.x;
    const int wid  = blockIdx.x * 4 + (tid >> 6);   // 0..383 = 12 ntiles x 32 ksteps
    const int lane = tid & 63;
    const int q    = lane >> 4, c = lane & 15;
    const int ntile = wid >> 5;
    const int kstep = wid & 31;
    const int n = ntile * 16 + c;                   // 0..191
    const int m = n >> 6;
    const float* W = (m == 0) ? Wq : (m == 1) ? Wk : Wv;
    const int ncol = n & 63;
    const int k0 = kstep * 32 + q * 8;
    u16x8 pk;
#pragma unroll
    for (int j = 0; j < 8; j++) pk[j] = f32_to_bf16(W[(size_t)(k0 + j) * H_ + ncol]);
    *(u16x8*)(Wt + (size_t)wid * 512 + lane * 8) = pk;
}

// ---- Kernel 1: QKV projection (round-11: 512-thr blocks, 4 waves/SIMD) -----
// Round-10 profile: proj 42us, MfmaUtil 5%, VALUBusy 8%, occupancy 16% ->
// residency-bound (2 waves/SIMD). Now: 512 blocks x 512 thr, block = 32 rows
// x all 192 n; wave (w>>2)=m-tile, (w&3)*48=n-chunk, 3 accs. 2 blocks/CU x 8
// waves = 4 waves/SIMD; cross-block overlap hides the staging stall.
__global__ __launch_bounds__(512, 4) void proj_kernel(
    const float* __restrict__ x, const unsigned short* __restrict__ Wt,
    unsigned short* __restrict__ Qb, unsigned short* __restrict__ Kb,
    unsigned short* __restrict__ Vb)
{
    __shared__ __align__(16) unsigned short xs[32][72];
    const int t    = threadIdx.x;
    const int r0   = blockIdx.x * 32;
    const int w    = t >> 6;
    const int lane = t & 63;
    const int quad = lane >> 4;
    const int c    = lane & 15;
    const int mh   = (w >> 2) * 16;   // wave's 16-row m-tile
    const int nh   = (w & 3) * 48;    // wave's 48-col n-chunk
    const int srow = t >> 4;          // 32 rows, 16 threads/row
    const int koff = (t & 15) * 4;    // 4 floats each

    f32x4 acc[3];
#pragma unroll
    for (int j = 0; j < 3; j++) acc[j] = {0.f, 0.f, 0.f, 0.f};

    const float* xp = x + (size_t)(r0 + srow) * C_ + koff;
    f32x4 v0 = *(const f32x4*)xp;     // prefetch tile kk=0

    for (int kk = 0; kk < C_; kk += 64) {
        u16x4 p;
#pragma unroll
        for (int i = 0; i < 4; i++) p[i] = f32_to_bf16(v0[i]);
        __syncthreads();
        *(u16x4*)&xs[srow][koff] = p;
        __syncthreads();
        if (kk + 64 < C_) v0 = *(const f32x4*)(xp + kk + 64);  // reg prefetch
#pragma unroll
        for (int ks = 0; ks < 64; ks += 32) {
            const bf16x8 a0 = *(const bf16x8*)&xs[mh + c][ks + quad * 8];
            const unsigned short* bp =
                Wt + ((size_t)(nh >> 4) * 32 + ((kk + ks) >> 5)) * 512 + lane * 8;
#pragma unroll
            for (int j = 0; j < 3; j++) {
                const bf16x8 bj = *(const bf16x8*)(bp + (size_t)j * 32 * 512);
                acc[j] = __builtin_amdgcn_mfma_f32_16x16x32_bf16(a0, bj, acc[j], 0, 0, 0);
            }
        }
    }

#pragma unroll
    for (int j = 0; j < 3; j++) {
        const int nt = nh + j * 16;      // 16-aligned -> wave-uniform select
        unsigned short* dst = (nt < 64) ? (Qb + nt)
                            : (nt < 128) ? (Kb + nt - 64)
                                         : (Vb + nt - 128);
#pragma unroll
        for (int r = 0; r < 4; r++) {
            const size_t row = (size_t)r0 + mh + quad * 4 + r;
            dst[row * H_ + c] = f32_to_bf16(acc[j][r]);
        }
    }
}

// ---- Kernel 2: K,V -> fragment order (Kf, Vf) (unchanged) ------------------
__global__ __launch_bounds__(256) void prep_kernel(
    const unsigned short* __restrict__ Kb, const unsigned short* __restrict__ Vb,
    unsigned short* __restrict__ Kf, unsigned short* __restrict__ Vf)
{
    __shared__ __align__(16) unsigned short vs[64][72];
    const int t    = threadIdx.x;
    const int r0   = blockIdx.x * 64;       // global row (64 | 4096: no b-cross)
    const int b    = r0 >> 12;
    const int kloc = r0 & 4095;
    const int w    = t >> 6, lane = t & 63, q = lane >> 4, c = lane & 15;

    // stage V tile: 64 rows x 64 cols; each thread stores 16 shorts
    const int row = t >> 2, col = (t & 3) * 16;
    const unsigned short* vsrc = Vb + (size_t)(r0 + row) * H_ + col;
    u16x8 va0 = *(const u16x8*)vsrc;
    u16x8 va1 = *(const u16x8*)(vsrc + 8);
    *(u16x8*)&vs[row][col]     = va0;
    *(u16x8*)&vs[row][col + 8] = va1;

    // K reorder (register-only)
    const unsigned short* ksrc = Kb + (size_t)(r0 + w * 16 + c) * H_ + q * 8;
    u16x8 k0v = *(const u16x8*)ksrc;
    u16x8 k1v = *(const u16x8*)(ksrc + 32);
    const size_t kt = (size_t)b * 256 + (kloc >> 4) + w;
    *(u16x8*)(Kf + kt * 1024 + lane * 8)       = k0v;
    *(u16x8*)(Kf + kt * 1024 + 512 + lane * 8) = k1v;

    __syncthreads();
    // V frags: wave w = h-tile
#pragma unroll
    for (int kh = 0; kh < 2; kh++) {
        u16x8 pv;
#pragma unroll
        for (int j = 0; j < 8; j++) pv[j] = vs[kh * 32 + q * 8 + j][w * 16 + c];
        const size_t k32 = (size_t)b * 128 + (kloc >> 5) + kh;
        *(u16x8*)(Vf + (k32 * 4 + w) * 512 + lane * 8) = pv;
    }
}

// ---- Kernel 3: causal flash attention (round-8 version, reverted) ----------
// Unit = wave = (b, qt, ks): queries qt*16..+15, keys [ks*512, ks*512+512).
// qt in LOW bits (XCD balance), ks in high bits. SEG=512 (round-10's SEG=256
// cost ~9us in merge/Opg traffic; reverted).
__global__ __launch_bounds__(256) void attn_kernel(
    const unsigned short* __restrict__ Qb, const unsigned short* __restrict__ Kf,
    const unsigned short* __restrict__ Vf, unsigned short* __restrict__ Opg,
    float* __restrict__ mlg)
{
    __shared__ __align__(16) unsigned short Pb[4][16][72];
    const int tid  = threadIdx.x;
    const int w    = tid >> 6;
    const int lane = tid & 63;
    const int quad = lane >> 4;
    const int c    = lane & 15;
    const int bid  = blockIdx.x;
    const int qt   = 255 - (bid & 255);       // qt descending within ks-group
    const int ks   = bid >> 8;
    const int g    = qt >> 5;                 // nseg-1
    if (ks > g) return;
    const int b    = w;                       // wave = batch (equal work lengths)
    const int q0   = qt * 16;
    const int k0   = ks * 512;
    const int kend = (q0 + 15 < k0 + 511) ? q0 + 15 : k0 + 511;
    const size_t bT = (size_t)b * T_;

    const unsigned short* qp = Qb + (bT + q0 + c) * H_ + quad * 8;
    const bf16x8 qB0 = *(const bf16x8*)qp;
    const bf16x8 qB1 = *(const bf16x8*)(qp + 32);

    f32x4 O[4];
#pragma unroll
    for (int tt = 0; tt < 4; tt++) O[tt] = {0.f, 0.f, 0.f, 0.f};
    float m = -1e30f, ls = 0.f;
    const float scale2 = 0.045084436f;        // (1/32)*log2(e): exp -> exp2

    unsigned short* P = &Pb[w][0][0];
    const int prow = c * 72;

    for (int kb = k0; kb <= kend; kb += 64) {
        const unsigned short* kfb = Kf + ((size_t)b * 256 + (kb >> 4)) * 1024 + lane * 8;
        f32x4 S[4];
#pragma unroll
        for (int tt = 0; tt < 4; tt++) {
            const bf16x8 kA0 = *(const bf16x8*)(kfb + tt * 1024);
            const bf16x8 kA1 = *(const bf16x8*)(kfb + tt * 1024 + 512);
            f32x4 s = {0.f, 0.f, 0.f, 0.f};
            s = __builtin_amdgcn_mfma_f32_16x16x32_bf16(kA0, qB0, s, 0, 0, 0);
            s = __builtin_amdgcn_mfma_f32_16x16x32_bf16(kA1, qB1, s, 0, 0, 0);
            S[tt] = s;
        }
        float sc[16];
        if (kb + 63 > q0) {                   // diagonal chunk: causal mask
#pragma unroll
            for (int tt = 0; tt < 4; tt++)
#pragma unroll
                for (int r = 0; r < 4; r++) {
                    const int key = kb + tt * 16 + quad * 4 + r;
                    sc[tt * 4 + r] = (key > q0 + c) ? -1e30f : S[tt][r] * scale2;
                }
        } else {
#pragma unroll
            for (int tt = 0; tt < 4; tt++)
#pragma unroll
                for (int r = 0; r < 4; r++) sc[tt * 4 + r] = S[tt][r] * scale2;
        }
        float mx = sc[0];
#pragma unroll
        for (int i = 1; i < 16; i++) mx = fmaxf(mx, sc[i]);
        mx = fmaxf(mx, __shfl_xor(mx, 16));
        mx = fmaxf(mx, __shfl_xor(mx, 32));
        const float mn    = fmaxf(m, mx);
        const float alpha = exp2_hw(m - mn);
        m = mn;
        float lsum = 0.f;
#pragma unroll
        for (int tt = 0; tt < 4; tt++) {
            u16x4 pk;
#pragma unroll
            for (int r = 0; r < 4; r++) {
                const float e = exp2_hw(sc[tt * 4 + r] - mn);
                lsum += e;
                pk[r] = f32_to_bf16(e);
            }
            *(u16x4*)(P + prow + tt * 16 + quad * 4) = pk;   // P[query][key]
        }
        ls = ls * alpha + lsum;                // per-lane partial (this quad's keys)
#pragma unroll
        for (int tt = 0; tt < 4; tt++)
#pragma unroll
            for (int r = 0; r < 4; r++) O[tt][r] *= alpha;

        const bf16x8 pB0 = *(const bf16x8*)(P + prow + quad * 8);
        const bf16x8 pB1 = *(const bf16x8*)(P + prow + 32 + quad * 8);

        const unsigned short* vfb = Vf + ((size_t)b * 128 + (kb >> 5)) * 2048 + lane * 8;
#pragma unroll
        for (int tt = 0; tt < 4; tt++) {
            const bf16x8 vA0 = *(const bf16x8*)(vfb + tt * 512);
            const bf16x8 vA1 = *(const bf16x8*)(vfb + 2048 + tt * 512);
            O[tt] = __builtin_amdgcn_mfma_f32_16x16x32_bf16(vA0, pB0, O[tt], 0, 0, 0);
            O[tt] = __builtin_amdgcn_mfma_f32_16x16x32_bf16(vA1, pB1, O[tt], 0, 0, 0);
        }
    }

    ls += __shfl_xor(ls, 16);                 // total l for query c
    ls += __shfl_xor(ls, 32);

    const size_t ustore = (size_t)b * NUNIT_ + qt + 16 * g * (g - 1) + g * (qt & 31) + ks;
#pragma unroll
    for (int tt = 0; tt < 4; tt++) {
        u16x4 pk;
#pragma unroll
        for (int r = 0; r < 4; r++) pk[r] = f32_to_bf16(O[tt][r]);
        *(u16x4*)(Opg + ustore * 1024 + c * 64 + tt * 16 + quad * 4) = pk;
    }
    if (lane < 16) {
        mlg[ustore * 32 + c]      = m;        // log2-domain max
        mlg[ustore * 32 + 16 + c] = ls;
    }
}

// ---- Kernel 4: merge segments + normalize (round-8 version, reverted) ------
__global__ __launch_bounds__(256) void merge_kernel(
    const unsigned short* __restrict__ Opg, const float* __restrict__ mlg,
    float* __restrict__ out)
{
    const int idx = blockIdx.x;               // b*256 + qt
    const int b   = idx >> 8;
    const int qt  = idx & 255;
    const int g   = qt >> 5;
    const int nseg = g + 1;
    const size_t base = (size_t)b * NUNIT_ + qt + 16 * g * (g - 1) + g * (qt & 31);
    const int t  = threadIdx.x;
    const int h  = t & 63;
    const int rg = t >> 6;
#pragma unroll
    for (int i = 0; i < 4; i++) {
        const int row = rg * 4 + i;
        float M = -1e30f;
        for (int s = 0; s < nseg; s++) M = fmaxf(M, mlg[(base + s) * 32 + row]);
        float L = 0.f, val = 0.f;
        for (int s = 0; s < nseg; s++) {
            const float e = exp2_hw(mlg[(base + s) * 32 + row] - M);
            L   = fmaf(mlg[(base + s) * 32 + 16 + row], e, L);
            val = fmaf(bf16_to_f32(Opg[(base + s) * 1024 + row * 64 + h]), e, val);
        }
        out[((size_t)b * T_ + qt * 16 + row) * H_ + h] = val / L;
    }
}

extern "C" void kernel_launch(void* const* d_in, const int* in_sizes, int n_in,
                              void* d_out, int out_size, void* d_ws, size_t ws_size,
                              hipStream_t stream) {
    const float* x  = (const float*)d_in[0];
    const float* Wq = (const float*)d_in[1];
    const float* Wk = (const float*)d_in[2];
    const float* Wv = (const float*)d_in[3];
    float* out = (float*)d_out;

    // ws: Qb|Kb|Vb|Kf|Vf (2 MiB each) | Wt 384K | Opg 9.2 MiB | mlg 576K
    unsigned short* Qb = (unsigned short*)d_ws;
    unsigned short* Kb = Qb + (size_t)BT_ * H_;
    unsigned short* Vb = Kb + (size_t)BT_ * H_;
    unsigned short* Kf = Vb + (size_t)BT_ * H_;
    unsigned short* Vf = Kf + (size_t)BT_ * H_;
    unsigned short* Wt = Vf + (size_t)BT_ * H_;
    unsigned short* Opg = Wt + (size_t)192 * C_;
    float*          mlg = (float*)(Opg + (size_t)B_ * NUNIT_ * 1024);

    wconv_kernel<<<96, 256, 0, stream>>>(Wq, Wk, Wv, Wt);
    proj_kernel<<<BT_ / 32, 512, 0, stream>>>(x, Wt, Qb, Kb, Vb);
    prep_kernel<<<BT_ / 64, 256, 0, stream>>>(Kb, Vb, Kf, Vf);
    attn_kernel<<<2048, 256, 0, stream>>>(Qb, Kf, Vf, Opg, mlg);
    merge_kernel<<<1024, 256, 0, stream>>>(Opg, mlg, out);
}

// Round 12
// 166.111 us; speedup vs baseline: 1.2381x; 1.0241x over previous
//
#include <hip/hip_runtime.h>

constexpr int B_  = 4;
constexpr int T_  = 4096;
constexpr int C_  = 1024;
constexpr int H_  = 64;
constexpr int BT_ = B_ * T_;
constexpr int NUNIT_ = 1152;   // 512-key work units per batch: sum_qt (qt/32+1)

typedef __attribute__((ext_vector_type(4))) float f32x4;
typedef __attribute__((ext_vector_type(8))) short bf16x8;
typedef __attribute__((ext_vector_type(8))) unsigned short u16x8;
typedef __attribute__((ext_vector_type(4))) unsigned short u16x4;

__device__ __forceinline__ unsigned short f32_to_bf16(float f) {
    union { float f; unsigned int u; } v;
    v.f = f;
    unsigned int r = v.u + 0x7FFFu + ((v.u >> 16) & 1u);  // RNE
    return (unsigned short)(r >> 16);
}
__device__ __forceinline__ float bf16_to_f32(unsigned short us) {
    union { unsigned int u; float f; } v;
    v.u = (unsigned int)us << 16;
    return v.f;
}
// 2^x via v_exp_f32 (hardware transcendental); __exp2f does not exist in HIP.
__device__ __forceinline__ float exp2_hw(float x) {
    return __builtin_amdgcn_exp2f(x);
}

// ---- Kernel 0: W -> fragment-order Wt (unchanged) --------------------------
__global__ __launch_bounds__(256) void wconv_kernel(
    const float* __restrict__ Wq, const float* __restrict__ Wk,
    const float* __restrict__ Wv, unsigned short* __restrict__ Wt)
{
    const int tid  = threadIdx.x;
    const int wid  = blockIdx.x * 4 + (tid >> 6);   // 0..383 = 12 ntiles x 32 ksteps
    const int lane = tid & 63;
    const int q    = lane >> 4, c = lane & 15;
    const int ntile = wid >> 5;
    const int kstep = wid & 31;
    const int n = ntile * 16 + c;                   // 0..191
    const int m = n >> 6;
    const float* W = (m == 0) ? Wq : (m == 1) ? Wk : Wv;
    const int ncol = n & 63;
    const int k0 = kstep * 32 + q * 8;
    u16x8 pk;
#pragma unroll
    for (int j = 0; j < 8; j++) pk[j] = f32_to_bf16(W[(size_t)(k0 + j) * H_ + ncol]);
    *(u16x8*)(Wt + (size_t)wid * 512 + lane * 8) = pk;
}

// ---- Kernel 1: QKV projection, fused fragment-order epilogue ---------------
// Round-12: prep_kernel deleted. The epilogue writes Qf/Kf/Vf (MFMA A/B frag
// order) DIRECTLY — same 4 scalar u16 stores per lane per n-tile the Kb/Vb
// path paid, so the reorder is free; saves one launch + 8 MiB round-trip.
// Qf/Kf[(b*256+t16)*1024 + half*512 + (q8*16+cc)*8 + j8] = X[t16*16+cc][half*32+q8*8+j8]
// Vf[((b*128+k32)*4+ht)*512 + (qv*16+cv)*8 + jv]         = V[k32*32+qv*8+jv][ht*16+cv]
__global__ __launch_bounds__(512, 4) void proj_kernel(
    const float* __restrict__ x, const unsigned short* __restrict__ Wt,
    unsigned short* __restrict__ Qf, unsigned short* __restrict__ Kf,
    unsigned short* __restrict__ Vf)
{
    __shared__ __align__(16) unsigned short xs[32][72];
    const int t    = threadIdx.x;
    const int r0   = blockIdx.x * 32;
    const int w    = t >> 6;
    const int lane = t & 63;
    const int quad = lane >> 4;
    const int c    = lane & 15;
    const int mh   = (w >> 2) * 16;   // wave's 16-row m-tile
    const int nh   = (w & 3) * 48;    // wave's 48-col n-chunk
    const int srow = t >> 4;          // 32 rows, 16 threads/row
    const int koff = (t & 15) * 4;    // 4 floats each

    f32x4 acc[3];
#pragma unroll
    for (int j = 0; j < 3; j++) acc[j] = {0.f, 0.f, 0.f, 0.f};

    const float* xp = x + (size_t)(r0 + srow) * C_ + koff;
    f32x4 v0 = *(const f32x4*)xp;     // prefetch tile kk=0

    for (int kk = 0; kk < C_; kk += 64) {
        u16x4 p;
#pragma unroll
        for (int i = 0; i < 4; i++) p[i] = f32_to_bf16(v0[i]);
        __syncthreads();
        *(u16x4*)&xs[srow][koff] = p;
        __syncthreads();
        if (kk + 64 < C_) v0 = *(const f32x4*)(xp + kk + 64);  // reg prefetch
#pragma unroll
        for (int ks = 0; ks < 64; ks += 32) {
            const bf16x8 a0 = *(const bf16x8*)&xs[mh + c][ks + quad * 8];
            const unsigned short* bp =
                Wt + ((size_t)(nh >> 4) * 32 + ((kk + ks) >> 5)) * 512 + lane * 8;
#pragma unroll
            for (int j = 0; j < 3; j++) {
                const bf16x8 bj = *(const bf16x8*)(bp + (size_t)j * 32 * 512);
                acc[j] = __builtin_amdgcn_mfma_f32_16x16x32_bf16(a0, bj, acc[j], 0, 0, 0);
            }
        }
    }

    // fused fragment-order epilogue
    const int S   = r0 + mh;          // global token base of this m-tile (16-aligned)
    const int bS  = S >> 12;
    const int cc0 = quad * 4;
#pragma unroll
    for (int j = 0; j < 3; j++) {
        const int nt = nh + j * 16;   // wave-uniform matrix select
        if (nt < 128) {               // Q (nt<64) or K
            const int d0 = (nt < 64) ? nt : nt - 64;
            unsigned short* base = (nt < 64) ? Qf : Kf;
            const int t16  = (S & 4095) >> 4;
            const int half = d0 >> 5;
            const int q8   = ((d0 >> 4) & 1) * 2 + (c >> 3);
            const int j8   = c & 7;
            unsigned short* p = base + ((size_t)(bS * 256 + t16)) * 1024
                              + half * 512 + q8 * 128 + j8;
#pragma unroll
            for (int r = 0; r < 4; r++) p[(cc0 + r) * 8] = f32_to_bf16(acc[j][r]);
        } else {                      // V
            const int d0  = nt - 128;
            const int k32 = (S & 4095) >> 5;
            const int ht  = d0 >> 4;
            const int sq  = (S & 31) >> 3;   // 0 or 2
            unsigned short* p = Vf + (((size_t)(bS * 128 + k32)) * 4 + ht) * 512 + c * 8;
#pragma unroll
            for (int r = 0; r < 4; r++) {
                const int cc = cc0 + r;
                p[(sq + (cc >> 3)) * 128 + (cc & 7)] = f32_to_bf16(acc[j][r]);
            }
        }
    }
}

// ---- Kernel 2: causal flash attention (round-8 core; Q from Qf) ------------
// Unit = wave = (b, qt, ks): queries qt*16..+15, keys [ks*512, ks*512+512).
// qt in LOW bits (XCD balance), ks in high bits.
__global__ __launch_bounds__(256) void attn_kernel(
    const unsigned short* __restrict__ Qf, const unsigned short* __restrict__ Kf,
    const unsigned short* __restrict__ Vf, unsigned short* __restrict__ Opg,
    float* __restrict__ mlg)
{
    __shared__ __align__(16) unsigned short Pb[4][16][72];
    const int tid  = threadIdx.x;
    const int w    = tid >> 6;
    const int lane = tid & 63;
    const int quad = lane >> 4;
    const int c    = lane & 15;
    const int bid  = blockIdx.x;
    const int qt   = 255 - (bid & 255);       // qt descending within ks-group
    const int ks   = bid >> 8;
    const int g    = qt >> 5;                 // nseg-1
    if (ks > g) return;
    const int b    = w;                       // wave = batch (equal work lengths)
    const int q0   = qt * 16;
    const int k0   = ks * 512;
    const int kend = (q0 + 15 < k0 + 511) ? q0 + 15 : k0 + 511;

    // Q B-frags: coalesced 1KB wave loads from fragment-order Qf
    const unsigned short* qp = Qf + ((size_t)b * 256 + qt) * 1024 + lane * 8;
    const bf16x8 qB0 = *(const bf16x8*)qp;
    const bf16x8 qB1 = *(const bf16x8*)(qp + 512);

    f32x4 O[4];
#pragma unroll
    for (int tt = 0; tt < 4; tt++) O[tt] = {0.f, 0.f, 0.f, 0.f};
    float m = -1e30f, ls = 0.f;
    const float scale2 = 0.045084436f;        // (1/32)*log2(e): exp -> exp2

    unsigned short* P = &Pb[w][0][0];
    const int prow = c * 72;

    for (int kb = k0; kb <= kend; kb += 64) {
        const unsigned short* kfb = Kf + ((size_t)b * 256 + (kb >> 4)) * 1024 + lane * 8;
        f32x4 S[4];
#pragma unroll
        for (int tt = 0; tt < 4; tt++) {
            const bf16x8 kA0 = *(const bf16x8*)(kfb + tt * 1024);
            const bf16x8 kA1 = *(const bf16x8*)(kfb + tt * 1024 + 512);
            f32x4 s = {0.f, 0.f, 0.f, 0.f};
            s = __builtin_amdgcn_mfma_f32_16x16x32_bf16(kA0, qB0, s, 0, 0, 0);
            s = __builtin_amdgcn_mfma_f32_16x16x32_bf16(kA1, qB1, s, 0, 0, 0);
            S[tt] = s;
        }
        float sc[16];
        if (kb + 63 > q0) {                   // diagonal chunk: causal mask
#pragma unroll
            for (int tt = 0; tt < 4; tt++)
#pragma unroll
                for (int r = 0; r < 4; r++) {
                    const int key = kb + tt * 16 + quad * 4 + r;
                    sc[tt * 4 + r] = (key > q0 + c) ? -1e30f : S[tt][r] * scale2;
                }
        } else {
#pragma unroll
            for (int tt = 0; tt < 4; tt++)
#pragma unroll
                for (int r = 0; r < 4; r++) sc[tt * 4 + r] = S[tt][r] * scale2;
        }
        float mx = sc[0];
#pragma unroll
        for (int i = 1; i < 16; i++) mx = fmaxf(mx, sc[i]);
        mx = fmaxf(mx, __shfl_xor(mx, 16));
        mx = fmaxf(mx, __shfl_xor(mx, 32));
        const float mn    = fmaxf(m, mx);
        const float alpha = exp2_hw(m - mn);
        m = mn;
        float lsum = 0.f;
#pragma unroll
        for (int tt = 0; tt < 4; tt++) {
            u16x4 pk;
#pragma unroll
            for (int r = 0; r < 4; r++) {
                const float e = exp2_hw(sc[tt * 4 + r] - mn);
                lsum += e;
                pk[r] = f32_to_bf16(e);
            }
            *(u16x4*)(P + prow + tt * 16 + quad * 4) = pk;   // P[query][key]
        }
        ls = ls * alpha + lsum;                // per-lane partial (this quad's keys)
#pragma unroll
        for (int tt = 0; tt < 4; tt++)
#pragma unroll
            for (int r = 0; r < 4; r++) O[tt][r] *= alpha;

        const bf16x8 pB0 = *(const bf16x8*)(P + prow + quad * 8);
        const bf16x8 pB1 = *(const bf16x8*)(P + prow + 32 + quad * 8);

        const unsigned short* vfb = Vf + ((size_t)b * 128 + (kb >> 5)) * 2048 + lane * 8;
#pragma unroll
        for (int tt = 0; tt < 4; tt++) {
            const bf16x8 vA0 = *(const bf16x8*)(vfb + tt * 512);
            const bf16x8 vA1 = *(const bf16x8*)(vfb + 2048 + tt * 512);
            O[tt] = __builtin_amdgcn_mfma_f32_16x16x32_bf16(vA0, pB0, O[tt], 0, 0, 0);
            O[tt] = __builtin_amdgcn_mfma_f32_16x16x32_bf16(vA1, pB1, O[tt], 0, 0, 0);
        }
    }

    ls += __shfl_xor(ls, 16);                 // total l for query c
    ls += __shfl_xor(ls, 32);

    const size_t ustore = (size_t)b * NUNIT_ + qt + 16 * g * (g - 1) + g * (qt & 31) + ks;
#pragma unroll
    for (int tt = 0; tt < 4; tt++) {
        u16x4 pk;
#pragma unroll
        for (int r = 0; r < 4; r++) pk[r] = f32_to_bf16(O[tt][r]);
        *(u16x4*)(Opg + ustore * 1024 + c * 64 + tt * 16 + quad * 4) = pk;
    }
    if (lane < 16) {
        mlg[ustore * 32 + c]      = m;        // log2-domain max
        mlg[ustore * 32 + 16 + c] = ls;
    }
}

// ---- Kernel 3: merge segments + normalize (unchanged) ----------------------
__global__ __launch_bounds__(256) void merge_kernel(
    const unsigned short* __restrict__ Opg, const float* __restrict__ mlg,
    float* __restrict__ out)
{
    const int idx = blockIdx.x;               // b*256 + qt
    const int b   = idx >> 8;
    const int qt  = idx & 255;
    const int g   = qt >> 5;
    const int nseg = g + 1;
    const size_t base = (size_t)b * NUNIT_ + qt + 16 * g * (g - 1) + g * (qt & 31);
    const int t  = threadIdx.x;
    const int h  = t & 63;
    const int rg = t >> 6;
#pragma unroll
    for (int i = 0; i < 4; i++) {
        const int row = rg * 4 + i;
        float M = -1e30f;
        for (int s = 0; s < nseg; s++) M = fmaxf(M, mlg[(base + s) * 32 + row]);
        float L = 0.f, val = 0.f;
        for (int s = 0; s < nseg; s++) {
            const float e = exp2_hw(mlg[(base + s) * 32 + row] - M);
            L   = fmaf(mlg[(base + s) * 32 + 16 + row], e, L);
            val = fmaf(bf16_to_f32(Opg[(base + s) * 1024 + row * 64 + h]), e, val);
        }
        out[((size_t)b * T_ + qt * 16 + row) * H_ + h] = val / L;
    }
}

extern "C" void kernel_launch(void* const* d_in, const int* in_sizes, int n_in,
                              void* d_out, int out_size, void* d_ws, size_t ws_size,
                              hipStream_t stream) {
    const float* x  = (const float*)d_in[0];
    const float* Wq = (const float*)d_in[1];
    const float* Wk = (const float*)d_in[2];
    const float* Wv = (const float*)d_in[3];
    float* out = (float*)d_out;

    // ws: Qf|Kf|Vf (2 MiB each) | Wt 384K | Opg 9.2 MiB | mlg 576K
    unsigned short* Qf = (unsigned short*)d_ws;
    unsigned short* Kf = Qf + (size_t)BT_ * H_;
    unsigned short* Vf = Kf + (size_t)BT_ * H_;
    unsigned short* Wt = Vf + (size_t)BT_ * H_;
    unsigned short* Opg = Wt + (size_t)192 * C_;
    float*          mlg = (float*)(Opg + (size_t)B_ * NUNIT_ * 1024);

    wconv_kernel<<<96, 256, 0, stream>>>(Wq, Wk, Wv, Wt);
    proj_kernel<<<BT_ / 32, 512, 0, stream>>>(x, Wt, Qf, Kf, Vf);
    attn_kernel<<<2048, 256, 0, stream>>>(Qf, Kf, Vf, Opg, mlg);
    merge_kernel<<<1024, 256, 0, stream>>>(Opg, mlg, out);
}